// Round 8
// baseline (132.011 us; speedup 1.0000x reference)
//
#include <hip/hip_runtime.h>

// Problem constants (fixed by setup_inputs): B=4096, D=512, H=W=64, N=4096.
#define B_ROWS 4096
#define N_COLS 4096
#define DIM    512

typedef __attribute__((ext_vector_type(8))) short short8;
typedef __attribute__((ext_vector_type(4))) float floatx4;

// bf16 round-to-nearest-even split helpers (bit-exact, no API dependence)
__device__ __forceinline__ unsigned short f2bf_rn(float f) {
    unsigned u = __float_as_uint(f);
    u += 0x7fffu + ((u >> 16) & 1u);
    return (unsigned short)(u >> 16);
}
__device__ __forceinline__ float bf2f(unsigned short h) {
    return __uint_as_float(((unsigned)h) << 16);
}

// Monotone float->uint map; (key<<32)|idx gives u64 atomicMin argmin with
// smallest-index tie-break (matches numpy argmin semantics).
__device__ __forceinline__ unsigned long long pack_key(float v, int idx) {
    unsigned u = __float_as_uint(v);
    u = (u & 0x80000000u) ? ~u : (u | 0x80000000u);
    return ((unsigned long long)u << 32) | (unsigned)idx;
}

// ---------------------------------------------------------------------------
// v9 layout: MFMA-fragment-tiled global storage for the split bf16 arrays.
// For each source array (X rows / W rows):
//   row-block R = row>>4 (16 rows), k-sub S = k>>5 (32 k), half h in {hi,lo},
//   granule l' = (row&15) + 16*((k>>3)&3)  (64 granules of 8 shorts).
// Linear (shorts): addr = (R*16 + S)*1024 + h*512 + l'*8.
// A wave's MFMA fragment load (16x16x32: lane l needs row l&15, k-chunk l>>4)
// is then EXACTLY base + l*8 shorts -> one coalesced global_load_dwordx4.
// dist uses NO LDS, NO barriers: pure reg-streamed MFMA with TLP hiding.
// ---------------------------------------------------------------------------

// One wave per row (4 rows/block): split fp32 row into bf16 hi/lo halves in
// fragment-tiled layout, compute exact fp32 ||row||^2, init packed argmin.
__global__ __launch_bounds__(256) void som_convert(
    const float* __restrict__ X, const float* __restrict__ Wt,
    unsigned short* __restrict__ Xc, unsigned short* __restrict__ Wc,
    float* __restrict__ x_sq, float* __restrict__ w_sq,
    unsigned long long* __restrict__ packed)
{
    int wave = threadIdx.x >> 6, lane = threadIdx.x & 63;
    int grow = blockIdx.x * 4 + wave;            // 0..8191
    bool isX = grow < B_ROWS;
    int local = isX ? grow : grow - B_ROWS;
    const float* src = isX ? (X + (size_t)local * DIM)
                           : (Wt + (size_t)local * DIM);
    const float4* p4 = (const float4*)src;
    float4 a = p4[lane * 2], b = p4[lane * 2 + 1];
    float f[8] = {a.x, a.y, a.z, a.w, b.x, b.y, b.z, b.w};
    short8 hi, lo;
    float s = 0.f;
    #pragma unroll
    for (int t = 0; t < 8; ++t) {
        unsigned short h = f2bf_rn(f[t]);
        hi[t] = (short)h;
        lo[t] = (short)f2bf_rn(f[t] - bf2f(h));
        s = fmaf(f[t], f[t], s);
    }
    // lane l holds k = 8l..8l+7  ->  S = l>>2, chunk c = l&3,
    // granule l' = (row&15) + 16*c; dest = (R*16+S)*1024 + h*512 + l'*8.
    int R = local >> 4, rr = local & 15;
    size_t off = ((size_t)R * 16 + (lane >> 2)) * 1024
               + (size_t)(rr + 16 * (lane & 3)) * 8;
    unsigned short* arr = isX ? Xc : Wc;
    *(short8*)(arr + off)       = hi;
    *(short8*)(arr + off + 512) = lo;
    #pragma unroll
    for (int off2 = 32; off2 >= 1; off2 >>= 1) s += __shfl_xor(s, off2, 64);
    if (lane == 0) {
        if (isX) { x_sq[grow] = s; packed[grow] = ~0ull; }
        else     { w_sq[local] = s; }
    }
}

// ---------------------------------------------------------------------------
// Split-bf16 distance GEMM v9: LDS-FREE. 128x128 tile, 4 waves (2x2), BK=32.
// Every operand fragment is a coalesced global_load_dwordx4 from the
// fragment-tiled arrays (L1/L2/L3-served; A-panel L2-hot since consecutive
// blocks share bm). No barriers, no __shared__, no vmcnt drains: each wave
// streams loads->MFMA independently; 4 blocks/CU (16 waves) of TLP hide
// per-wave load latency. LDS-BW bottleneck of v1-v8 (96KB/block/K-step
// through 85 B/cyc banks) is gone.
// Per-acc MFMA order identical to v1 (ah*bh, ah*bl, al*bh; kt ascending)
// => bit-exact.
// ---------------------------------------------------------------------------
__global__ __launch_bounds__(256, 4) void som_dist_v9(
    const unsigned short* __restrict__ Xc, const unsigned short* __restrict__ Wc,
    const float* __restrict__ w_sq, unsigned long long* __restrict__ packed)
{
    const int tid  = threadIdx.x;
    const int wave = tid >> 6, lane = tid & 63;
    const int quad = lane >> 4, t16 = lane & 15;
    const int wr = wave >> 1, wc = wave & 1;       // 2x2 wave grid (64x64/wave)
    const int bm = blockIdx.y, bn = blockIdx.x;

    // Fragment bases: R = bm*8 + wr*4 + i  (A), bn*8 + wc*4 + j  (B).
    // frag(i, kt, h) at + i*16384 + kt*1024 + h*512 (shorts), lane-linear.
    const unsigned short* Abase = Xc + (size_t)(bm * 8 + wr * 4) * 16384 + lane * 8;
    const unsigned short* Bbase = Wc + (size_t)(bn * 8 + wc * 4) * 16384 + lane * 8;

    floatx4 acc[4][4];
    #pragma unroll
    for (int i = 0; i < 4; ++i)
        #pragma unroll
        for (int j = 0; j < 4; ++j) acc[i][j] = (floatx4){0.f, 0.f, 0.f, 0.f};

    #pragma unroll 2
    for (int kt = 0; kt < 16; ++kt) {
        const unsigned short* ak = Abase + kt * 1024;
        const unsigned short* bk = Bbase + kt * 1024;
        short8 ah[4], bh[4], bl[4], al[4];
        #pragma unroll
        for (int i = 0; i < 4; ++i) ah[i] = *(const short8*)(ak + i * 16384);
        #pragma unroll
        for (int j = 0; j < 4; ++j) bh[j] = *(const short8*)(bk + j * 16384);
        #pragma unroll
        for (int j = 0; j < 4; ++j) bl[j] = *(const short8*)(bk + j * 16384 + 512);
        #pragma unroll
        for (int i = 0; i < 4; ++i) al[i] = *(const short8*)(ak + i * 16384 + 512);

        #pragma unroll
        for (int i = 0; i < 4; ++i)
            #pragma unroll
            for (int j = 0; j < 4; ++j)
                acc[i][j] = __builtin_amdgcn_mfma_f32_16x16x32_bf16(
                    ah[i], bh[j], acc[i][j], 0, 0, 0);
        #pragma unroll
        for (int i = 0; i < 4; ++i)
            #pragma unroll
            for (int j = 0; j < 4; ++j)
                acc[i][j] = __builtin_amdgcn_mfma_f32_16x16x32_bf16(
                    ah[i], bl[j], acc[i][j], 0, 0, 0);
        #pragma unroll
        for (int i = 0; i < 4; ++i)
            #pragma unroll
            for (int j = 0; j < 4; ++j)
                acc[i][j] = __builtin_amdgcn_mfma_f32_16x16x32_bf16(
                    al[i], bh[j], acc[i][j], 0, 0, 0);
    }

    // Epilogue: val = w_sq - 2*dot (x_sq is per-row constant, irrelevant to
    // argmin). C/D layout: col = t16, row = quad*4 + reg  [m89/m91].
    const int col0 = bn * 128 + wc * 64 + t16;
    float wq[4];
    #pragma unroll
    for (int j = 0; j < 4; ++j) wq[j] = w_sq[col0 + j * 16];
    const int row_base = bm * 128 + wr * 64 + quad * 4;
    #pragma unroll
    for (int i = 0; i < 4; ++i) {
        #pragma unroll
        for (int r = 0; r < 4; ++r) {
            unsigned long long best = ~0ull;
            #pragma unroll
            for (int j = 0; j < 4; ++j) {
                float val = fmaf(-2.f, acc[i][j][r], wq[j]);
                unsigned long long key = pack_key(val, col0 + j * 16);
                best = (key < best) ? key : best;
            }
            #pragma unroll
            for (int m = 1; m <= 8; m <<= 1) {     // reduce 16-lane col group
                unsigned long long o = __shfl_xor(best, m, 64);
                best = (o < best) ? o : best;
            }
            if (t16 == 0)
                atomicMin(&packed[row_base + i * 16 + r], best);
        }
    }
}

// Unpack argmin, qe = sqrt(max(||x||^2 + val, 0)).
// d_out: bmu_indices (4096 x 2) flat, then qe (4096), all float. (unchanged)
__global__ __launch_bounds__(256) void som_finalize(
    const unsigned long long* __restrict__ packed,
    const float* __restrict__ x_sq, float* __restrict__ out)
{
    int b = blockIdx.x * 256 + threadIdx.x;  // 0..4095
    unsigned long long p = packed[b];
    unsigned idx = (unsigned)(p & 0xffffffffull);
    unsigned key = (unsigned)(p >> 32);
    unsigned u = (key & 0x80000000u) ? (key & 0x7fffffffu) : ~key;
    float val = __uint_as_float(u);
    float sq = fmaxf(x_sq[b] + val, 0.f);
    out[2 * b]     = (float)(idx >> 6);   // y = idx / 64
    out[2 * b + 1] = (float)(idx & 63);   // x = idx % 64
    out[2 * B_ROWS + b] = sqrtf(sq);
}

extern "C" void kernel_launch(void* const* d_in, const int* in_sizes, int n_in,
                              void* d_out, int out_size, void* d_ws, size_t ws_size,
                              hipStream_t stream) {
    const float* X  = (const float*)d_in[0];   // (4096, 512)
    const float* Wt = (const float*)d_in[1];   // (64, 64, 512) -> (4096, 512)
    float* out = (float*)d_out;

    // ws layout: [0,32K) packed u64[4096]; [32K,48K) x_sq; [48K,64K) w_sq;
    // [64K, 64K+8M) Xc fragment-tiled; [64K+8M, 64K+16M) Wc fragment-tiled.
    unsigned long long* packed = (unsigned long long*)d_ws;
    float* x_sq = (float*)((char*)d_ws + (32 << 10));
    float* w_sq = (float*)((char*)d_ws + (48 << 10));
    unsigned short* Xc = (unsigned short*)((char*)d_ws + (64 << 10));
    unsigned short* Wc = (unsigned short*)((char*)d_ws + (64 << 10) + ((size_t)B_ROWS * DIM * 2 * 2));

    som_convert<<<dim3((B_ROWS + N_COLS) / 4), dim3(256), 0, stream>>>(
        X, Wt, Xc, Wc, x_sq, w_sq, packed);
    som_dist_v9<<<dim3(N_COLS / 128, B_ROWS / 128), dim3(256), 0, stream>>>(
        Xc, Wc, w_sq, packed);
    som_finalize<<<dim3(B_ROWS / 256), dim3(256), 0, stream>>>(packed, x_sq, out);
}